// Round 2
// baseline (441.995 us; speedup 1.0000x reference)
//
#include <hip/hip_runtime.h>
#include <math.h>

// Problem: B=64, N_total=1029, D=768, r=64, E=4, TOPK=1.
// Fully fused: one prep kernel packs all weights as bf16 hi/lo MFMA fragments
// (L2-resident, ~452 KB); one main kernel does proj+gelu -> moe -> up*gamma
// per 64-token block with zero __syncthreads and no global intermediate.
//
// bf16x3 split: a*b ~= ah*bh + ah*bl + al*bh  (error ~2^-15 rel).
// Fragment convention (both A and B operands): lane (lg=l>>4, lr=l&15) holds
// M[lr][k0 + lg*8 + e], e=0..7 — identical k-slot map on both operands makes
// the dot product invariant to the HW's internal k ordering.
// C/D: col = lane&15, row = lg*4 + reg  [HW-verified].

#define GELU(v) (0.5f*(v)*(1.0f + erff((v)*0.70710678118654752440f)))

typedef __attribute__((ext_vector_type(8))) short bf16x8;
typedef __attribute__((ext_vector_type(4))) float f32x4;

#define MFMA(a,b,c) __builtin_amdgcn_mfma_f32_16x16x32_bf16((a),(b),(c),0,0,0)

__device__ __forceinline__ unsigned pk_hi(float a, float b) {
  return (__float_as_uint(a) >> 16) | (__float_as_uint(b) & 0xFFFF0000u);
}
__device__ __forceinline__ float f_lo(float a) {
  return a - __uint_as_float(__float_as_uint(a) & 0xFFFF0000u);
}
union U8 { unsigned u[4]; bf16x8 v; uint4 q; };
__device__ __forceinline__ bf16x8 hi8(float4 f0, float4 f1) {
  U8 r; r.u[0]=pk_hi(f0.x,f0.y); r.u[1]=pk_hi(f0.z,f0.w);
        r.u[2]=pk_hi(f1.x,f1.y); r.u[3]=pk_hi(f1.z,f1.w); return r.v;
}
__device__ __forceinline__ bf16x8 lo8(float4 f0, float4 f1) {
  U8 r; r.u[0]=pk_hi(f_lo(f0.x),f_lo(f0.y)); r.u[1]=pk_hi(f_lo(f0.z),f_lo(f0.w));
        r.u[2]=pk_hi(f_lo(f1.x),f_lo(f1.y)); r.u[3]=pk_hi(f_lo(f1.z),f_lo(f1.w)); return r.v;
}

// ---------------------------------------------------------------------------
// Fragment-pack layout in ws (1 KB per fragment = 64 lanes x 16 B):
//   fid 0..191   : Wd   idx = ((kt*2+kc)*4 + nt)*2 + part      (kt<12,kc<2,nt<4)
//   fid 192..259 : We/Wg idx = 192 + ((kc*17+nt)*2 + part)     (nt<17; nt==16 -> Wg cols 256..259, zero-pad 260..271)
//   fid 260..451 : Wu   idx = 260 + ((nt*2+kc)*2 + part)       (nt<48)
// value at (lane,e) = M[col = nt*16+lr][k = k0 + lg*8 + e]
// ---------------------------------------------------------------------------
__global__ __launch_bounds__(256) void prep_pack(
    const float* __restrict__ Wd, const float* __restrict__ Wg,
    const float* __restrict__ We, const float* __restrict__ Wu,
    char* __restrict__ wp)
{
  int fid = blockIdx.x*4 + (threadIdx.x >> 6);
  if (fid >= 452) return;
  int lane = threadIdx.x & 63, lg = lane >> 4, lr = lane & 15;
  float v[8];
  int part;
  if (fid < 192) {
    part = fid & 1; int q = fid >> 1;
    int nt = q & 3; q >>= 2; int kc = q & 1, kt = q >> 1;
    int col = nt*16 + lr, k = kt*64 + kc*32 + lg*8;
    const float* p = Wd + (size_t)col*768 + k;
    #pragma unroll
    for (int e = 0; e < 8; ++e) v[e] = p[e];
  } else if (fid < 260) {
    int f = fid - 192; part = f & 1; int q = f >> 1;
    int nt = q % 17, kc = q / 17;
    int col = nt*16 + lr, k = kc*32 + lg*8;
    if (col < 256) {
      const float* p = We + (size_t)col*64 + k;
      #pragma unroll
      for (int e = 0; e < 8; ++e) v[e] = p[e];
    } else if (col < 260) {
      const float* p = Wg + (size_t)(col-256)*64 + k;
      #pragma unroll
      for (int e = 0; e < 8; ++e) v[e] = p[e];
    } else {
      #pragma unroll
      for (int e = 0; e < 8; ++e) v[e] = 0.f;
    }
  } else {
    int f = fid - 260; part = f & 1; int q = f >> 1;
    int kc = q & 1, nt = q >> 1;
    int col = nt*16 + lr, k = kc*32 + lg*8;
    const float* p = Wu + (size_t)col*64 + k;
    #pragma unroll
    for (int e = 0; e < 8; ++e) v[e] = p[e];
  }
  U8 r;
  if (part == 0) {
    r.u[0]=pk_hi(v[0],v[1]); r.u[1]=pk_hi(v[2],v[3]);
    r.u[2]=pk_hi(v[4],v[5]); r.u[3]=pk_hi(v[6],v[7]);
  } else {
    r.u[0]=pk_hi(f_lo(v[0]),f_lo(v[1])); r.u[1]=pk_hi(f_lo(v[2]),f_lo(v[3]));
    r.u[2]=pk_hi(f_lo(v[4]),f_lo(v[5])); r.u[3]=pk_hi(f_lo(v[6]),f_lo(v[7]));
  }
  *(uint4*)(wp + (size_t)fid*1024 + lane*16) = r.q;
}

// ---------------------------------------------------------------------------
// Fused main kernel. Grid 1029 x 256. Each wave owns 16 consecutive tokens
// end-to-end; waves never share data -> no __syncthreads anywhere.
// ---------------------------------------------------------------------------
__global__ __launch_bounds__(256) void fused(
    const float* __restrict__ x, const float* __restrict__ be,
    const float* __restrict__ gamma, const char* __restrict__ wp,
    float* __restrict__ out)
{
  __shared__ float sF[4][16][68];   // per-wave private bounce tile (17.4 KB)
  const int tid = threadIdx.x, bm = blockIdx.x;
  const int wv = tid >> 6, l = tid & 63, lg = l >> 4, lr = l & 15;
  const char* wpL = wp + l*16;

  // ---- phase 1: t = gelu(x . Wd^T), t in C-layout registers -------------
  const float* xrow = x + (size_t)(bm*64 + wv*16 + lr)*768;
  f32x4 t4[4];
  #pragma unroll
  for (int nt = 0; nt < 4; ++nt)
    #pragma unroll
    for (int r = 0; r < 4; ++r) t4[nt][r] = 0.f;

  for (int kt = 0; kt < 12; ++kt) {
    #pragma unroll
    for (int kc = 0; kc < 2; ++kc) {
      const float* xp = xrow + kt*64 + kc*32 + lg*8;
      float4 f0 = *(const float4*)xp, f1 = *(const float4*)(xp + 4);
      bf16x8 ah = hi8(f0, f1), al = lo8(f0, f1);
      const char* bp = wpL + (size_t)((kt*2 + kc)*8)*1024;
      #pragma unroll
      for (int nt = 0; nt < 4; ++nt) {
        bf16x8 bh = *(const bf16x8*)(bp + (nt*2+0)*1024);
        bf16x8 bl = *(const bf16x8*)(bp + (nt*2+1)*1024);
        t4[nt] = MFMA(ah, bh, t4[nt]);
        t4[nt] = MFMA(ah, bl, t4[nt]);
        t4[nt] = MFMA(al, bh, t4[nt]);
      }
    }
  }
  // gelu + stash t into wave-private LDS slice (C-layout -> [row][col])
  #pragma unroll
  for (int nt = 0; nt < 4; ++nt)
    #pragma unroll
    for (int r = 0; r < 4; ++r) {
      float g = GELU(t4[nt][r]);
      t4[nt][r] = g;
      sF[wv][lg*4 + r][nt*16 + lr] = g;
    }

  // ---- phase 2: gating + experts ----------------------------------------
  // A-fragments of t (lane reads row lr of wave slice)
  bf16x8 pah[2], pal[2];
  #pragma unroll
  for (int kc = 0; kc < 2; ++kc) {
    const float* ap = &sF[wv][lr][kc*32 + lg*8];
    float4 a0 = *(const float4*)ap, a1 = *(const float4*)(ap + 4);
    pah[kc] = hi8(a0, a1); pal[kc] = lo8(a0, a1);
  }
  // logits tile (We-pack nt=16): cols 256+e for e<4
  f32x4 lac;
  #pragma unroll
  for (int r = 0; r < 4; ++r) lac[r] = 0.f;
  #pragma unroll
  for (int kc = 0; kc < 2; ++kc) {
    const char* bp = wpL + (size_t)(192 + (kc*17 + 16)*2)*1024;
    bf16x8 bh = *(const bf16x8*)(bp);
    bf16x8 bl = *(const bf16x8*)(bp + 1024);
    lac = MFMA(pah[kc], bh, lac);
    lac = MFMA(pah[kc], bl, lac);
    lac = MFMA(pal[kc], bh, lac);
  }
  // per-row top-1 select (rows lg*4+r live in lanes (l&48)+e, reg r)
  const int tokbase = bm*64 + wv*16 + lg*4;
  float w_[4]; int ei_[4];
  #pragma unroll
  for (int r = 0; r < 4; ++r) {
    float lt = lac[r];
    int base = l & 48;
    float l0 = __shfl(lt, base+0), l1 = __shfl(lt, base+1);
    float l2 = __shfl(lt, base+2), l3 = __shfl(lt, base+3);
    int ei = 0; float lm = l0;
    if (l1 > lm) { lm = l1; ei = 1; }
    if (l2 > lm) { lm = l2; ei = 2; }
    if (l3 > lm) { lm = l3; ei = 3; }
    float s = expf(l0-lm) + expf(l1-lm) + expf(l2-lm) + expf(l3-lm);
    float w = 1.0f / s;
    int pos = (tokbase + r) % 1029;         // first 5 tokens of each row: no MoE
    if (pos < 5) w = 0.0f;
    w_[r] = w; ei_[r] = ei;
  }
  // per-expert compute, masked fold into sel
  f32x4 sel[4];
  #pragma unroll
  for (int j = 0; j < 4; ++j)
    #pragma unroll
    for (int r = 0; r < 4; ++r) sel[j][r] = 0.f;
  #pragma unroll
  for (int e = 0; e < 4; ++e) {
    f32x4 de[4];
    #pragma unroll
    for (int j = 0; j < 4; ++j)
      #pragma unroll
      for (int r = 0; r < 4; ++r) de[j][r] = 0.f;
    #pragma unroll
    for (int kc = 0; kc < 2; ++kc) {
      const char* bp = wpL + (size_t)(192 + (kc*17 + e*4)*2)*1024;
      #pragma unroll
      for (int j = 0; j < 4; ++j) {
        bf16x8 bh = *(const bf16x8*)(bp + (j*2+0)*1024);
        bf16x8 bl = *(const bf16x8*)(bp + (j*2+1)*1024);
        de[j] = MFMA(pah[kc], bh, de[j]);
        de[j] = MFMA(pah[kc], bl, de[j]);
        de[j] = MFMA(pal[kc], bh, de[j]);
      }
    }
    #pragma unroll
    for (int j = 0; j < 4; ++j)
      #pragma unroll
      for (int r = 0; r < 4; ++r)
        sel[j][r] = (ei_[r] == e) ? de[j][r] : sel[j][r];
  }
  // full = t + w*(sel + be[ei])  -> write back into wave slice
  #pragma unroll
  for (int r = 0; r < 4; ++r) {
    #pragma unroll
    for (int j = 0; j < 4; ++j) {
      int col = j*16 + lr;
      float full = t4[j][r] + w_[r] * (sel[j][r] + be[ei_[r]*64 + col]);
      sF[wv][lg*4 + r][col] = full;
    }
  }

  // ---- phase 3: out = (full . Wu^T) * gamma -----------------------------
  bf16x8 a3h[2], a3l[2];
  #pragma unroll
  for (int kc = 0; kc < 2; ++kc) {
    const float* ap = &sF[wv][lr][kc*32 + lg*8];
    float4 a0 = *(const float4*)ap, a1 = *(const float4*)(ap + 4);
    a3h[kc] = hi8(a0, a1); a3l[kc] = lo8(a0, a1);
  }
  #pragma unroll 4
  for (int nt = 0; nt < 48; ++nt) {
    const char* bp = wpL + (size_t)(260 + nt*4)*1024;
    f32x4 o;
    #pragma unroll
    for (int r = 0; r < 4; ++r) o[r] = 0.f;
    bf16x8 b0h = *(const bf16x8*)(bp);
    bf16x8 b0l = *(const bf16x8*)(bp + 1024);
    bf16x8 b1h = *(const bf16x8*)(bp + 2048);
    bf16x8 b1l = *(const bf16x8*)(bp + 3072);
    o = MFMA(a3h[0], b0h, o);
    o = MFMA(a3h[0], b0l, o);
    o = MFMA(a3l[0], b0h, o);
    o = MFMA(a3h[1], b1h, o);
    o = MFMA(a3h[1], b1l, o);
    o = MFMA(a3l[1], b1h, o);
    int col = nt*16 + lr;
    float g = gamma[col];
    #pragma unroll
    for (int r = 0; r < 4; ++r)
      out[(size_t)(tokbase + r)*768 + col] = o[r] * g;
  }
}

extern "C" void kernel_launch(void* const* d_in, const int* in_sizes, int n_in,
                              void* d_out, int out_size, void* d_ws, size_t ws_size,
                              hipStream_t stream) {
  const float* x     = (const float*)d_in[0];
  const float* Wd    = (const float*)d_in[1];
  const float* Wg    = (const float*)d_in[2];
  const float* We    = (const float*)d_in[3];
  const float* be    = (const float*)d_in[4];
  const float* Wu    = (const float*)d_in[5];
  const float* gamma = (const float*)d_in[6];
  float* out = (float*)d_out;
  char* wp   = (char*)d_ws;    // 452 KB packed weights

  prep_pack<<<113, 256, 0, stream>>>(Wd, Wg, We, Wu, wp);
  fused<<<1029, 256, 0, stream>>>(x, be, gamma, (const char*)wp, out);
}

// Round 3
// 428.671 us; speedup vs baseline: 1.0311x; 1.0311x over previous
//
#include <hip/hip_runtime.h>
#include <math.h>

// Problem: B=64, N_total=1029, D=768, r=64, E=4, TOPK=1.
// Fully fused, latency-fixed version:
//  - prep_pack converts all weights to bf16 hi/lo MFMA fragments, 1 KB each,
//    grouped into 57 chunks of 8 KB in exact compute order.
//  - fused kernel double-buffers chunks in LDS via global_load_lds (width 16),
//    2-phase pipeline {STAGE(next); compute(cur); barrier}; weights are read
//    once per BLOCK (shared by 4 waves) instead of once per wave from L2.
//
// bf16x3 split: a*b ~= ah*bh + ah*bl + al*bh  (error ~2^-15 rel).
// Fragment map (A and B identical): lane (lg=l>>4,lr=l&15) holds
// M[lr][k0+lg*8+e], e=0..7.  C/D: col=lane&15, row=lg*4+reg [HW-verified].

#define GELU(v) (0.5f*(v)*(1.0f + erff((v)*0.70710678118654752440f)))

typedef __attribute__((ext_vector_type(8))) short bf16x8;
typedef __attribute__((ext_vector_type(4))) float f32x4;

#define MFMA(a,b,c) __builtin_amdgcn_mfma_f32_16x16x32_bf16((a),(b),(c),0,0,0)

__device__ __forceinline__ unsigned pk_hi(float a, float b) {
  return (__float_as_uint(a) >> 16) | (__float_as_uint(b) & 0xFFFF0000u);
}
__device__ __forceinline__ float f_lo(float a) {
  return a - __uint_as_float(__float_as_uint(a) & 0xFFFF0000u);
}
union U8 { unsigned u[4]; bf16x8 v; uint4 q; };
__device__ __forceinline__ bf16x8 hi8(float4 f0, float4 f1) {
  U8 r; r.u[0]=pk_hi(f0.x,f0.y); r.u[1]=pk_hi(f0.z,f0.w);
        r.u[2]=pk_hi(f1.x,f1.y); r.u[3]=pk_hi(f1.z,f1.w); return r.v;
}
__device__ __forceinline__ bf16x8 lo8(float4 f0, float4 f1) {
  U8 r; r.u[0]=pk_hi(f_lo(f0.x),f_lo(f0.y)); r.u[1]=pk_hi(f_lo(f0.z),f_lo(f0.w));
        r.u[2]=pk_hi(f_lo(f1.x),f_lo(f1.y)); r.u[3]=pk_hi(f_lo(f1.z),f_lo(f1.w)); return r.v;
}

// async copy of one 1 KB fragment (64 lanes x 16 B).
// g: per-lane global src (base + lane*16). d: wave-uniform LDS fragment base
// (HW writes lane data at d + lane*16).
__device__ __forceinline__ void cp16(const char* g, char* d, int lane) {
#if __has_builtin(__builtin_amdgcn_global_load_lds)
  __builtin_amdgcn_global_load_lds(
      (const __attribute__((address_space(1))) unsigned int*)g,
      (__attribute__((address_space(3))) unsigned int*)d, 16, 0, 0);
#else
  *(uint4*)(d + lane*16) = *(const uint4*)g;
#endif
}

// ---------------------------------------------------------------------------
// Fragment/chunk layout in wp (fid = chunk*8 + slot, 1 KB per fragment):
//  chunks  0..23 : Wd    chunk c = kt*2+kc (kt<12,kc<2), slot = nt*2+part (nt<4)
//  chunk   24    : logits: slot = kc*2+part (kc<2), slots 4..7 zero pad
//  chunks 25..32 : experts: chunk = 25 + e*2 + kc, slot = j*2+part (j<4)
//  chunks 33..56 : Wu    chunk c: 2 n-tiles nt=2c+u, slot = u*4 + kc*2 + part
// value at (lane,e) = Bmat[col = tile*16+lr][k = kc*32 + lg*8 + e]
// ---------------------------------------------------------------------------
__global__ __launch_bounds__(256) void prep_pack(
    const float* __restrict__ Wd, const float* __restrict__ Wg,
    const float* __restrict__ We, const float* __restrict__ Wu,
    char* __restrict__ wp)
{
  int fid = blockIdx.x*4 + (threadIdx.x >> 6);
  if (fid >= 456) return;
  int l = threadIdx.x & 63, lg = l >> 4, lr = l & 15;
  float v[8];
  int part = 0;
  if (fid < 192) {
    int c = fid >> 3, s = fid & 7;
    int kt = c >> 1, kc = c & 1, nt = s >> 1; part = s & 1;
    const float* p = Wd + (size_t)(nt*16 + lr)*768 + kt*64 + kc*32 + lg*8;
    #pragma unroll
    for (int e = 0; e < 8; ++e) v[e] = p[e];
  } else if (fid < 264) {
    int f = fid - 192, ch = f >> 3, s = f & 7;
    if (ch == 0) {
      part = s & 1;
      int kc = (s >> 1) & 1;
      if (s < 4 && lr < 4) {
        const float* p = Wg + lr*64 + kc*32 + lg*8;
        #pragma unroll
        for (int e = 0; e < 8; ++e) v[e] = p[e];
      } else {
        #pragma unroll
        for (int e = 0; e < 8; ++e) v[e] = 0.f;
      }
    } else {
      int e_ = (ch - 1) >> 1, kc = (ch - 1) & 1, j = s >> 1; part = s & 1;
      const float* p = We + (size_t)(e_*64 + j*16 + lr)*64 + kc*32 + lg*8;
      #pragma unroll
      for (int e = 0; e < 8; ++e) v[e] = p[e];
    }
  } else {
    int f = fid - 264;
    int nt = f >> 2, kc = (f >> 1) & 1; part = f & 1;
    const float* p = Wu + (size_t)(nt*16 + lr)*64 + kc*32 + lg*8;
    #pragma unroll
    for (int e = 0; e < 8; ++e) v[e] = p[e];
  }
  U8 rr;
  if (part == 0) {
    rr.u[0]=pk_hi(v[0],v[1]); rr.u[1]=pk_hi(v[2],v[3]);
    rr.u[2]=pk_hi(v[4],v[5]); rr.u[3]=pk_hi(v[6],v[7]);
  } else {
    rr.u[0]=pk_hi(f_lo(v[0]),f_lo(v[1])); rr.u[1]=pk_hi(f_lo(v[2]),f_lo(v[3]));
    rr.u[2]=pk_hi(f_lo(v[4]),f_lo(v[5])); rr.u[3]=pk_hi(f_lo(v[6]),f_lo(v[7]));
  }
  *(uint4*)(wp + (size_t)fid*1024 + (size_t)l*16) = rr.q;
}

// ---------------------------------------------------------------------------
// Fused main kernel. Grid 1029 x 256 (4 waves, 16 tokens/wave).
// ---------------------------------------------------------------------------
__global__ __launch_bounds__(256, 4) void fused(
    const float* __restrict__ x, const float* __restrict__ be,
    const float* __restrict__ gamma, const char* __restrict__ wp,
    float* __restrict__ out)
{
  __shared__ float sF[4][16][68];      // per-wave private bounce tile
  __shared__ char stage[2][8192];      // weight-chunk double buffer
  const int tid = threadIdx.x, bm = blockIdx.x;
  const int wv = tid >> 6, l = tid & 63, lg = l >> 4, lr = l & 15;
  const int tokbase = bm*64 + wv*16 + lg*4;

#define STAGE(chunk, buf) do { \
    const char* _g = wp + (size_t)(chunk)*8192 + (size_t)(wv*2)*1024 + (size_t)l*16; \
    char* _d = &stage[buf][wv*2048]; \
    cp16(_g, _d, l); \
    cp16(_g + 1024, _d + 1024, l); \
  } while (0)

  // ---- phase 1: t = gelu(x . Wd^T) --------------------------------------
  const float* xrow = x + (size_t)(bm*64 + wv*16 + lr)*768 + lg*8;
  f32x4 t4[4];
  #pragma unroll
  for (int nt = 0; nt < 4; ++nt)
    #pragma unroll
    for (int r = 0; r < 4; ++r) t4[nt][r] = 0.f;

  float4 xa = *(const float4*)xrow, xb = *(const float4*)(xrow + 4);
  STAGE(0, 0);
  __syncthreads();
  for (int c = 0; c < 24; ++c) {
    float4 xa2 = xa, xb2 = xb;
    if (c < 23) {
      STAGE(c + 1, (c + 1) & 1);
      const float* xp = xrow + (c + 1)*32;
      xa2 = *(const float4*)xp; xb2 = *(const float4*)(xp + 4);
    }
    bf16x8 ah = hi8(xa, xb), al = lo8(xa, xb);
    const char* bp = &stage[c & 1][l*16];
    #pragma unroll
    for (int nt = 0; nt < 4; ++nt) {
      bf16x8 bh = *(const bf16x8*)(bp + (size_t)(nt*2)*1024);
      bf16x8 bl = *(const bf16x8*)(bp + (size_t)(nt*2 + 1)*1024);
      t4[nt] = MFMA(ah, bh, t4[nt]);
      t4[nt] = MFMA(ah, bl, t4[nt]);
      t4[nt] = MFMA(al, bh, t4[nt]);
    }
    __syncthreads();
    xa = xa2; xb = xb2;
  }

  // ---- phase 2: gating + experts ----------------------------------------
  STAGE(24, 0);                         // logits chunk
  STAGE(25, 1);                         // expert0/kc0 chunk
  #pragma unroll
  for (int nt = 0; nt < 4; ++nt)
    #pragma unroll
    for (int r = 0; r < 4; ++r) {
      float g = GELU(t4[nt][r]);
      t4[nt][r] = g;
      sF[wv][lg*4 + r][nt*16 + lr] = g;
    }
  bf16x8 pah[2], pal[2];
  #pragma unroll
  for (int kc = 0; kc < 2; ++kc) {
    const float* ap = &sF[wv][lr][kc*32 + lg*8];
    float4 a0 = *(const float4*)ap, a1 = *(const float4*)(ap + 4);
    pah[kc] = hi8(a0, a1); pal[kc] = lo8(a0, a1);
  }
  __syncthreads();

  f32x4 lac;
  #pragma unroll
  for (int r = 0; r < 4; ++r) lac[r] = 0.f;
  {
    const char* bp = &stage[0][l*16];
    bf16x8 b0h = *(const bf16x8*)(bp);
    bf16x8 b0l = *(const bf16x8*)(bp + 1024);
    bf16x8 b1h = *(const bf16x8*)(bp + 2048);
    bf16x8 b1l = *(const bf16x8*)(bp + 3072);
    lac = MFMA(pah[0], b0h, lac); lac = MFMA(pah[0], b0l, lac); lac = MFMA(pal[0], b0h, lac);
    lac = MFMA(pah[1], b1h, lac); lac = MFMA(pah[1], b1l, lac); lac = MFMA(pal[1], b1h, lac);
  }
  float w_[4]; int ei_[4];
  #pragma unroll
  for (int r = 0; r < 4; ++r) {
    float lt = lac[r];
    int base = l & 48;
    float l0 = __shfl(lt, base + 0), l1 = __shfl(lt, base + 1);
    float l2 = __shfl(lt, base + 2), l3 = __shfl(lt, base + 3);
    int ei = 0; float lm = l0;
    if (l1 > lm) { lm = l1; ei = 1; }
    if (l2 > lm) { lm = l2; ei = 2; }
    if (l3 > lm) { lm = l3; ei = 3; }
    float s = expf(l0 - lm) + expf(l1 - lm) + expf(l2 - lm) + expf(l3 - lm);
    float w = 1.0f / s;
    int pos = (tokbase + r) % 1029;     // first 5 tokens of each row: no MoE
    if (pos < 5) w = 0.0f;
    w_[r] = w; ei_[r] = ei;
  }
  __syncthreads();
  STAGE(26, 0);

  f32x4 de[4], sel[4];
  #pragma unroll
  for (int j = 0; j < 4; ++j)
    #pragma unroll
    for (int r = 0; r < 4; ++r) { de[j][r] = 0.f; sel[j][r] = 0.f; }

  #pragma unroll
  for (int s = 1; s <= 8; ++s) {
    const int e_ = (s - 1) >> 1, kc = (s - 1) & 1, cb = s & 1;
    const char* bp = &stage[cb][l*16];
    #pragma unroll
    for (int j = 0; j < 4; ++j) {
      bf16x8 bh = *(const bf16x8*)(bp + (size_t)(j*2)*1024);
      bf16x8 bl = *(const bf16x8*)(bp + (size_t)(j*2 + 1)*1024);
      de[j] = MFMA(pah[kc], bh, de[j]);
      de[j] = MFMA(pah[kc], bl, de[j]);
      de[j] = MFMA(pal[kc], bh, de[j]);
    }
    if (kc == 1) {
      #pragma unroll
      for (int j = 0; j < 4; ++j)
        #pragma unroll
        for (int r = 0; r < 4; ++r) {
          sel[j][r] = (ei_[r] == e_) ? de[j][r] : sel[j][r];
          de[j][r] = 0.f;
        }
    }
    __syncthreads();
    if (s <= 6) STAGE(26 + s, cb);
  }

  // ---- phase 3: out = (full . Wu^T) * gamma -----------------------------
  STAGE(33, 1);
  STAGE(34, 0);
  #pragma unroll
  for (int r = 0; r < 4; ++r)
    #pragma unroll
    for (int j = 0; j < 4; ++j) {
      int col = j*16 + lr;
      float full = t4[j][r] + w_[r] * (sel[j][r] + be[ei_[r]*64 + col]);
      sF[wv][lg*4 + r][col] = full;
    }
  bf16x8 a3h[2], a3l[2];
  #pragma unroll
  for (int kc = 0; kc < 2; ++kc) {
    const float* ap = &sF[wv][lr][kc*32 + lg*8];
    float4 a0 = *(const float4*)ap, a1 = *(const float4*)(ap + 4);
    a3h[kc] = hi8(a0, a1); a3l[kc] = lo8(a0, a1);
  }
  __syncthreads();

  for (int c = 0; c < 24; ++c) {
    const int cb = (c + 1) & 1;
    const char* bpc = &stage[cb][l*16];
    #pragma unroll
    for (int u = 0; u < 2; ++u) {
      const char* bp = bpc + u*4096;
      bf16x8 b0h = *(const bf16x8*)(bp);
      bf16x8 b0l = *(const bf16x8*)(bp + 1024);
      bf16x8 b1h = *(const bf16x8*)(bp + 2048);
      bf16x8 b1l = *(const bf16x8*)(bp + 3072);
      f32x4 o;
      #pragma unroll
      for (int r = 0; r < 4; ++r) o[r] = 0.f;
      o = MFMA(a3h[0], b0h, o); o = MFMA(a3h[0], b0l, o); o = MFMA(a3l[0], b0h, o);
      o = MFMA(a3h[1], b1h, o); o = MFMA(a3h[1], b1l, o); o = MFMA(a3l[1], b1h, o);
      const int col = (c*2 + u)*16 + lr;
      const float gv = gamma[col];
      #pragma unroll
      for (int r = 0; r < 4; ++r)
        out[(size_t)(tokbase + r)*768 + col] = o[r] * gv;
    }
    __syncthreads();
    if (c + 2 < 24) STAGE(35 + c, cb);
  }
#undef STAGE
}

extern "C" void kernel_launch(void* const* d_in, const int* in_sizes, int n_in,
                              void* d_out, int out_size, void* d_ws, size_t ws_size,
                              hipStream_t stream) {
  const float* x     = (const float*)d_in[0];
  const float* Wd    = (const float*)d_in[1];
  const float* Wg    = (const float*)d_in[2];
  const float* We    = (const float*)d_in[3];
  const float* be    = (const float*)d_in[4];
  const float* Wu    = (const float*)d_in[5];
  const float* gamma = (const float*)d_in[6];
  float* out = (float*)d_out;
  char* wp   = (char*)d_ws;    // 456 KB packed weights

  prep_pack<<<114, 256, 0, stream>>>(Wd, Wg, We, Wu, wp);
  fused<<<1029, 256, 0, stream>>>(x, be, gamma, (const char*)wp, out);
}